// Round 2
// baseline (134.098 us; speedup 1.0000x reference)
//
#include <hip/hip_runtime.h>
#include <math.h>

#define HID 128
#define SPB 64    // samples per chunk per block
#define TPB 512   // 8 waves; 3 blocks/CU (42.5KB LDS) -> three barrier domains
#define GRIDB 768 // persistent, 3 blocks/CU on 256 CUs

typedef __bf16 bf16;
typedef bf16 bf16x8 __attribute__((ext_vector_type(8)));
typedef bf16 bf16x4 __attribute__((ext_vector_type(4)));
typedef float floatx4 __attribute__((ext_vector_type(4)));

// rcp-based tanh; packed f32 (v_pk_*) for everything but the trans ops.
__device__ __forceinline__ floatx4 tanh4(floatx4 z) {
    floatx4 t = z * 2.885390081777927f;                  // 2 v_pk_mul
    floatx4 e = { __builtin_amdgcn_exp2f(t[0]), __builtin_amdgcn_exp2f(t[1]),
                  __builtin_amdgcn_exp2f(t[2]), __builtin_amdgcn_exp2f(t[3]) };
    e = e + 1.0f;                                        // 2 v_pk_add
    floatx4 r = { __builtin_amdgcn_rcpf(e[0]), __builtin_amdgcn_rcpf(e[1]),
                  __builtin_amdgcn_rcpf(e[2]), __builtin_amdgcn_rcpf(e[3]) };
    return 1.0f - 2.0f * r;                              // 2 v_pk_fma
}

// ALL-TRANSPOSED formulation. MFMA 16x16x32 layouts:
//   A-frag: lane holds A[m=lane&15][k=quad*8+idx]
//   B-frag: lane holds B[k=quad*8+idx][n=lane&15]
//   C/D:    lane/reg holds D[row=quad*4+reg][col=lane&15]
// GEMM1t: Z2^T = W2^T @ H1^T   (A=W2^T frags in REGS aW2T, B=H1^T in LDS)
// GEMM2t: S^T  = W2 @ G2^T     (A=W2 rows in REGS aW2, B=G2^T in LDS)
// GEMM3t: dV^T = W1 @ G1^T     (A=W1 reg frag, B=G1^T IN-PLACE in sH1, same-wave)
// LDS: sBuf (32KB) is staged with W2^T A-frags once, each wave copies its 8
// frags to registers, then sBuf is reused as sH1 (16KB) + sG2 (16KB).
// Barriers per chunk: B (sH1 ready), C (sG2 ready), F (sDV+state ready).
// Wave w (8 waves): wlo=w&3, whi=w>>2.
//   phase1: st=wlo, kt in {2whi,2whi+1}
//   GEMM1t/phase3: jt in {2wlo,2wlo+1}, st in {2whi,2whi+1}
//   GEMM2t/phase5/GEMM3t: it in {2wlo,2wlo+1} (jt2_own=wlo), st in {2whi,2whi+1}

__global__ __launch_bounds__(TPB, 6)
void lnn_kernel(const float* __restrict__ X,
                const float* __restrict__ W1,
                const float* __restrict__ b1,
                const float* __restrict__ b2,
                const float* __restrict__ W3,
                const float* __restrict__ W2,
                float* __restrict__ out,
                int B, int nchunk)
{
    __shared__ __align__(16) bf16 sBuf[16384]; // 32KB: W2^T A-frags at staging, then sH1|sG2
    __shared__ __align__(16) float sW1r[4][HID]; // W1 row-major (packed loads)
    __shared__ __align__(16) float sB1[HID], sB2[HID], sW3[HID];
    __shared__ __align__(16) float sFeat[2][SPB][4];
    __shared__ float sQd[2][SPB][2];
    __shared__ __align__(16) float sDV[4][SPB][4]; // partials per jt2

    bf16* const sH1 = sBuf;        // 16KB H1^T B-frags [(st*4+kt)*64+l]*8 (G1^T in-place later)
    bf16* const sG2 = sBuf + 8192; // 16KB G2^T B-frags [(st*4+jt2)*64+l]*8

    const int tid  = threadIdx.x;
    const int w    = tid >> 6;
    const int lane = tid & 63;
    const int lrow = lane & 15;
    const int lq   = lane >> 4;
    const int wlo  = w & 3;
    const int whi  = w >> 2;

    // ---------------- one-time staging ----------------
    { // W1 rows (coalesced, 1 elem/thread) + biases/W3
        int r = tid >> 7, j = tid & (HID - 1);
        sW1r[r][j] = W1[r * HID + j];
    }
    if (tid < HID) sB1[tid] = b1[tid];
    else if (tid < 2 * HID) sB2[tid - HID] = b2[tid - HID];
    else if (tid < 3 * HID) sW3[tid - 2 * HID] = W3[tid - 2 * HID];

    // W2^T A-frags (column-segment gather) into sBuf, 4 frag lines/thread
    #pragma unroll
    for (int tt = 0; tt < 4; ++tt) {
        int e = tid + tt * TPB;       // 0..2047
        int t = e >> 6, l = e & 63;
        int jt = t >> 2, kt = t & 3;
        int lr = l & 15, q = l >> 4;
        bf16x8 f;
        #pragma unroll
        for (int idx = 0; idx < 8; ++idx)
            f[idx] = (bf16)W2[(32*kt + 8*q + idx) * HID + 16*jt + lr];
        *reinterpret_cast<bf16x8*>(&sBuf[e * 8]) = f;
    }
    // W1 A-frag for GEMM3t, K-range jt2=wlo (rows>=4 zero)
    bf16x8 bW1 = {};
    if (lrow < 4) {
        const float4* wp = reinterpret_cast<const float4*>(&W1[lrow*HID + 32*wlo + 8*lq]);
        float4 a = wp[0], b = wp[1];
        bW1[0]=(bf16)a.x; bW1[1]=(bf16)a.y; bW1[2]=(bf16)a.z; bW1[3]=(bf16)a.w;
        bW1[4]=(bf16)b.x; bW1[5]=(bf16)b.y; bW1[6]=(bf16)b.z; bW1[7]=(bf16)b.w;
    }
    // GEMM2t A-frags: W2 rows from global -> regs, once
    bf16x8 aW2[2][4];
    #pragma unroll
    for (int u = 0; u < 2; ++u) {
        const float* rbase = &W2[(16*(2*wlo + u) + lrow) * HID + 8*lq];
        #pragma unroll
        for (int jt2 = 0; jt2 < 4; ++jt2) {
            const float4* rp = reinterpret_cast<const float4*>(rbase + 32*jt2);
            float4 r0 = rp[0], r1 = rp[1];
            bf16x8 g;
            g[0]=(bf16)r0.x; g[1]=(bf16)r0.y; g[2]=(bf16)r0.z; g[3]=(bf16)r0.w;
            g[4]=(bf16)r1.x; g[5]=(bf16)r1.y; g[6]=(bf16)r1.z; g[7]=(bf16)r1.w;
            aW2[u][jt2] = g;
        }
    }
    // chunk-0 state prefetch (wave 7)
    if (tid >= TPB - SPB) {
        int s  = tid - (TPB - SPB);
        int g  = (int)blockIdx.x * SPB + s;
        int gc = g < B ? g : (B - 1);
        float4 x = reinterpret_cast<const float4*>(X)[gc];
        float s1, c1, s2, c2;
        __sincosf(x.x, &s1, &c1);
        __sincosf(x.y, &s2, &c2);
        sFeat[0][s][0]=s1; sFeat[0][s][1]=c1; sFeat[0][s][2]=s2; sFeat[0][s][3]=c2;
        sQd[0][s][0]=x.z;  sQd[0][s][1]=x.w;
    }
    __syncthreads(); // staging image of W2^T frags complete

    // GEMM1t A-frags: own (jt,kt) fragments LDS -> regs, then sBuf is reusable
    bf16x8 aW2T[2][4];
    #pragma unroll
    for (int u = 0; u < 2; ++u)
        #pragma unroll
        for (int kt = 0; kt < 4; ++kt)
            aW2T[u][kt] = *reinterpret_cast<const bf16x8*>(&sBuf[(((2*wlo+u)*4 + kt)*64 + lane)*8]);
    __syncthreads(); // all frag copies done; sBuf now free for sH1/sG2

    #pragma unroll 1
    for (int c = 0; c < nchunk; ++c) {
        const int par = c & 1;
        const int s0  = (c * GRIDB + (int)blockIdx.x) * SPB;

        // ---- Phase 1: H1^T B-frags; tile (st=wlo, kt=2whi+h); lane: s=16wlo+lrow ----
        {
            int s = 16 * wlo + lrow;
            float f0 = sFeat[par][s][0], f1 = sFeat[par][s][1];
            float f2 = sFeat[par][s][2], f3 = sFeat[par][s][3];
            #pragma unroll
            for (int h = 0; h < 2; ++h) {
                int kt = 2 * whi + h;
                int jb = 32 * kt + 8 * lq;
                floatx4 w0a = *reinterpret_cast<const floatx4*>(&sW1r[0][jb]);
                floatx4 w0b = *reinterpret_cast<const floatx4*>(&sW1r[0][jb+4]);
                floatx4 w1a = *reinterpret_cast<const floatx4*>(&sW1r[1][jb]);
                floatx4 w1b = *reinterpret_cast<const floatx4*>(&sW1r[1][jb+4]);
                floatx4 w2a = *reinterpret_cast<const floatx4*>(&sW1r[2][jb]);
                floatx4 w2b = *reinterpret_cast<const floatx4*>(&sW1r[2][jb+4]);
                floatx4 w3a = *reinterpret_cast<const floatx4*>(&sW1r[3][jb]);
                floatx4 w3b = *reinterpret_cast<const floatx4*>(&sW1r[3][jb+4]);
                floatx4 bba = *reinterpret_cast<const floatx4*>(&sB1[jb]);
                floatx4 bbb = *reinterpret_cast<const floatx4*>(&sB1[jb+4]);
                floatx4 za = bba + f0*w0a + f1*w1a + f2*w2a + f3*w3a; // 8 v_pk_fma
                floatx4 zb = bbb + f0*w0b + f1*w1b + f2*w2b + f3*w3b;
                floatx4 ha = tanh4(za);
                floatx4 hb = tanh4(zb);
                bf16x8 hf;
                hf[0]=(bf16)ha[0]; hf[1]=(bf16)ha[1]; hf[2]=(bf16)ha[2]; hf[3]=(bf16)ha[3];
                hf[4]=(bf16)hb[0]; hf[5]=(bf16)hb[1]; hf[6]=(bf16)hb[2]; hf[7]=(bf16)hb[3];
                *reinterpret_cast<bf16x8*>(&sH1[((wlo*4 + kt)*64 + lane)*8]) = hf;
            }
        }
        __syncthreads(); // B: sH1 ready

        // ---- GEMM1t: Z2^T = W2^T @ H1^T ; A from regs; out tiles (jt=2wlo+t, st=2whi+s) ----
        floatx4 acc[2][2];
        #pragma unroll
        for (int t = 0; t < 2; ++t)
            #pragma unroll
            for (int s = 0; s < 2; ++s) acc[t][s] = floatx4{0.f,0.f,0.f,0.f};
        #pragma unroll
        for (int kt = 0; kt < 4; ++kt) {
            bf16x8 b0 = *reinterpret_cast<const bf16x8*>(&sH1[(((2*whi  )*4 + kt)*64 + lane)*8]);
            bf16x8 b1v = *reinterpret_cast<const bf16x8*>(&sH1[(((2*whi+1)*4 + kt)*64 + lane)*8]);
            acc[0][0] = __builtin_amdgcn_mfma_f32_16x16x32_bf16(aW2T[0][kt], b0,  acc[0][0], 0,0,0);
            acc[0][1] = __builtin_amdgcn_mfma_f32_16x16x32_bf16(aW2T[0][kt], b1v, acc[0][1], 0,0,0);
            acc[1][0] = __builtin_amdgcn_mfma_f32_16x16x32_bf16(aW2T[1][kt], b0,  acc[1][0], 0,0,0);
            acc[1][1] = __builtin_amdgcn_mfma_f32_16x16x32_bf16(aW2T[1][kt], b1v, acc[1][1], 0,0,0);
        }

        // ---- Phase 3: G2^T = (1-tanh^2(Z2+b2))*W3 -> B-frags via ds_write_b64 ----
        #pragma unroll
        for (int t = 0; t < 2; ++t) {
            int jb = 16*(2*wlo + t) + 4*lq;   // j for r=0
            floatx4 b2v = *reinterpret_cast<const floatx4*>(&sB2[jb]);
            floatx4 w3v = *reinterpret_cast<const floatx4*>(&sW3[jb]);
            int q2  = 2*t + (lq >> 1);
            int sub = 4 * (lq & 1);
            #pragma unroll
            for (int s = 0; s < 2; ++s) {
                int st = 2*whi + s;
                floatx4 h = tanh4(acc[t][s] + b2v);
                floatx4 gv = (1.0f - h*h) * w3v;           // packed
                bf16x4 g;
                g[0]=(bf16)gv[0]; g[1]=(bf16)gv[1]; g[2]=(bf16)gv[2]; g[3]=(bf16)gv[3];
                *reinterpret_cast<bf16x4*>(&sG2[((st*4 + wlo)*64 + (q2*16 + lrow))*8 + sub]) = g;
            }
        }
        __syncthreads(); // C: sG2 (G2^T) ready

        // ---- GEMM2t: S^T = W2 @ G2^T ; out tiles (it=2wlo+u, st=2whi+s) ----
        #pragma unroll
        for (int t = 0; t < 2; ++t)
            #pragma unroll
            for (int s = 0; s < 2; ++s) acc[t][s] = floatx4{0.f,0.f,0.f,0.f};
        #pragma unroll
        for (int jt2 = 0; jt2 < 4; ++jt2) {
            bf16x8 g0 = *reinterpret_cast<const bf16x8*>(&sG2[(((2*whi  )*4 + jt2)*64 + lane)*8]);
            bf16x8 g1 = *reinterpret_cast<const bf16x8*>(&sG2[(((2*whi+1)*4 + jt2)*64 + lane)*8]);
            acc[0][0] = __builtin_amdgcn_mfma_f32_16x16x32_bf16(aW2[0][jt2], g0, acc[0][0], 0,0,0);
            acc[0][1] = __builtin_amdgcn_mfma_f32_16x16x32_bf16(aW2[0][jt2], g1, acc[0][1], 0,0,0);
            acc[1][0] = __builtin_amdgcn_mfma_f32_16x16x32_bf16(aW2[1][jt2], g0, acc[1][0], 0,0,0);
            acc[1][1] = __builtin_amdgcn_mfma_f32_16x16x32_bf16(aW2[1][jt2], g1, acc[1][1], 0,0,0);
        }
        // (no barrier: phase5 below touches only wave-private sH1 slots)

        // ---- Phase 5: G1^T = (1-h1^2)*S^T, IN-PLACE in sH1 (own slots, b64 RMW) ----
        #pragma unroll
        for (int u = 0; u < 2; ++u) {
            int q2  = 2*u + (lq >> 1);
            int sub = 4 * (lq & 1);
            #pragma unroll
            for (int s = 0; s < 2; ++s) {
                int st  = 2*whi + s;
                int off = ((st*4 + wlo)*64 + (q2*16 + lrow))*8 + sub;
                bf16x4 h4 = *reinterpret_cast<const bf16x4*>(&sH1[off]);
                floatx4 hf = { (float)h4[0], (float)h4[1], (float)h4[2], (float)h4[3] };
                floatx4 gv = (1.0f - hf*hf) * acc[u][s];   // packed
                bf16x4 g;
                g[0]=(bf16)gv[0]; g[1]=(bf16)gv[1]; g[2]=(bf16)gv[2]; g[3]=(bf16)gv[3];
                *reinterpret_cast<bf16x4*>(&sH1[off]) = g;
            }
        }

        // prefetch next chunk's state (wave 7), overlapped with GEMM3t
        if (tid >= TPB - SPB && c + 1 < nchunk) {
            int s  = tid - (TPB - SPB);
            int g  = ((c + 1) * GRIDB + (int)blockIdx.x) * SPB + s;
            int gc = g < B ? g : (B - 1);
            float4 x = reinterpret_cast<const float4*>(X)[gc];
            float s1, c1, s2, c2;
            __sincosf(x.x, &s1, &c1);
            __sincosf(x.y, &s2, &c2);
            int np = par ^ 1;
            sFeat[np][s][0]=s1; sFeat[np][s][1]=c1; sFeat[np][s][2]=s2; sFeat[np][s][3]=c2;
            sQd[np][s][0]=x.z;  sQd[np][s][1]=x.w;
        }

        // ---- GEMM3t: dV^T partial (jt2=wlo) = W1 @ G1^T (same-wave tiles, from sH1) ----
        {
            bf16x8 g0 = *reinterpret_cast<const bf16x8*>(&sH1[(((2*whi  )*4 + wlo)*64 + lane)*8]);
            bf16x8 g1 = *reinterpret_cast<const bf16x8*>(&sH1[(((2*whi+1)*4 + wlo)*64 + lane)*8]);
            floatx4 d0 = __builtin_amdgcn_mfma_f32_16x16x32_bf16(bW1, g0, floatx4{0.f,0.f,0.f,0.f}, 0,0,0);
            floatx4 d1 = __builtin_amdgcn_mfma_f32_16x16x32_bf16(bW1, g1, floatx4{0.f,0.f,0.f,0.f}, 0,0,0);
            if (lane < 16) { // quad 0: regs r = dV[k=r] for sample s=16st+lane
                *reinterpret_cast<float4*>(&sDV[wlo][16*(2*whi  ) + lane][0]) =
                    make_float4(d0[0], d0[1], d0[2], d0[3]);
                *reinterpret_cast<float4*>(&sDV[wlo][16*(2*whi+1) + lane][0]) =
                    make_float4(d1[0], d1[1], d1[2], d1[3]);
            }
        }
        __syncthreads(); // F: sDV + next-chunk state visible

        // ---- Epilogue: analytic dynamics + 2x2 solve (wave 0, tid<64) ----
        if (tid < SPB) {
            int g = s0 + tid;
            if (g < B) {
                floatx4 d0 = *reinterpret_cast<const floatx4*>(&sDV[0][tid][0]);
                floatx4 d1 = *reinterpret_cast<const floatx4*>(&sDV[1][tid][0]);
                floatx4 d2 = *reinterpret_cast<const floatx4*>(&sDV[2][tid][0]);
                floatx4 d3 = *reinterpret_cast<const floatx4*>(&sDV[3][tid][0]);
                floatx4 dV = (d0 + d1) + (d2 + d3);        // packed
                float s1 = sFeat[par][tid][0], c1 = sFeat[par][tid][1];
                float s2 = sFeat[par][tid][2], c2 = sFeat[par][tid][3];
                float w1 = sQd[par][tid][0],  w2 = sQd[par][tid][1];
                float cosD = c1 * c2 + s1 * s2;
                float sinD = s1 * c2 - c1 * s2;
                float dVt1 = dV[0] * c1 - dV[1] * s1;   // dV/dt1
                float dVt2 = dV[2] * c2 - dV[3] * s2;   // dV/dt2
                float sT = w1 * w2 * sinD;              // dT/dt1 = -sT, dT/dt2 = +sT
                float cw = sinD * (w2 - w1);
                float rhs1 = (-sT - dVt1) - w2 * cw;
                float rhs2 = ( sT - dVt2) - w1 * cw;
                float det = 2.0f - cosD * cosD;         // det(M) in [1,2]
                float inv = __builtin_amdgcn_rcpf(det);
                float qdd1 = (rhs1 - cosD * rhs2) * inv;
                float qdd2 = (2.0f * rhs2 - cosD * rhs1) * inv;
                *reinterpret_cast<float4*>(&out[4 * g]) = make_float4(w1, w2, qdd1, qdd2);
            }
        }
    }
}

extern "C" void kernel_launch(void* const* d_in, const int* in_sizes, int n_in,
                              void* d_out, int out_size, void* d_ws, size_t ws_size,
                              hipStream_t stream) {
    const float* X  = (const float*)d_in[0];
    const float* W1 = (const float*)d_in[1];
    const float* b1 = (const float*)d_in[2];
    const float* W2 = (const float*)d_in[3];
    const float* b2 = (const float*)d_in[4];
    const float* W3 = (const float*)d_in[5];
    // d_in[6] = b3: constant offset on V, vanishes in all gradients
    float* out = (float*)d_out;
    int B = in_sizes[0] / 4;
    int nchunk = (B + GRIDB * SPB - 1) / (GRIDB * SPB);
    lnn_kernel<<<GRIDB, TPB, 0, stream>>>(X, W1, b1, b2, W3, W2, out, B, nchunk);
}

// Round 3
// 91.033 us; speedup vs baseline: 1.4731x; 1.4731x over previous
//
#include <hip/hip_runtime.h>
#include <math.h>

#define HID 128
#define SPB 64    // samples per chunk per block
#define TPB 512   // 8 waves; 2 blocks/CU (42.5KB LDS, <=128 VGPR)
#define GRIDB 512 // persistent, 2 blocks/CU on 256 CUs exactly

typedef __bf16 bf16;
typedef bf16 bf16x8 __attribute__((ext_vector_type(8)));
typedef bf16 bf16x4 __attribute__((ext_vector_type(4)));
typedef float floatx4 __attribute__((ext_vector_type(4)));

// rcp-based tanh; packed f32 (v_pk_*) for everything but the trans ops.
__device__ __forceinline__ floatx4 tanh4(floatx4 z) {
    floatx4 t = z * 2.885390081777927f;                  // 2 v_pk_mul
    floatx4 e = { __builtin_amdgcn_exp2f(t[0]), __builtin_amdgcn_exp2f(t[1]),
                  __builtin_amdgcn_exp2f(t[2]), __builtin_amdgcn_exp2f(t[3]) };
    e = e + 1.0f;                                        // 2 v_pk_add
    floatx4 r = { __builtin_amdgcn_rcpf(e[0]), __builtin_amdgcn_rcpf(e[1]),
                  __builtin_amdgcn_rcpf(e[2]), __builtin_amdgcn_rcpf(e[3]) };
    return 1.0f - 2.0f * r;                              // 2 v_pk_fma
}

// ALL-TRANSPOSED formulation. MFMA 16x16x32 layouts:
//   A-frag: lane holds A[m=lane&15][k=quad*8+idx]
//   B-frag: lane holds B[k=quad*8+idx][n=lane&15]
//   C/D:    lane/reg holds D[row=quad*4+reg][col=lane&15]
// GEMM1t: Z2^T = W2^T @ H1^T   (A=W2^T frags in REGS aW2T, B=H1^T in LDS)
// GEMM2t: S^T  = W2 @ G2^T     (A=W2 rows in REGS aW2, B=G2^T in LDS)
// GEMM3t: dV^T = W1 @ G1^T     (A=W1 reg frag, B=G1^T IN-PLACE in sH1, same-wave)
// LDS: sBuf (32KB) is staged with W2^T A-frags once, each wave copies its 8
// frags to registers, then sBuf is reused as sH1 (16KB) + sG2 (16KB).
// Barriers per chunk: B (sH1 ready), C (sG2 ready), F (sDV+state ready).
// REGISTER BUDGET NOTE: aW2T(32)+aW2(32)+bW1(4)+acc(16)+temps ~= 120 VGPR.
// __launch_bounds__(512,4) -> 4 waves/SIMD -> 128 VGPR budget: fits.
// (512,6) -> 85 budget -> catastrophic scratch spill (measured r2: 200MB HBM
// traffic, 72us spill-bound). Do NOT raise min-waves without cutting frags.
// Wave w (8 waves): wlo=w&3, whi=w>>2.

__global__ __launch_bounds__(TPB, 4)
void lnn_kernel(const float* __restrict__ X,
                const float* __restrict__ W1,
                const float* __restrict__ b1,
                const float* __restrict__ b2,
                const float* __restrict__ W3,
                const float* __restrict__ W2,
                float* __restrict__ out,
                int B, int nchunk)
{
    __shared__ __align__(16) bf16 sBuf[16384]; // 32KB: W2^T A-frags at staging, then sH1|sG2
    __shared__ __align__(16) float sW1r[4][HID]; // W1 row-major (packed loads)
    __shared__ __align__(16) float sB1[HID], sB2[HID], sW3[HID];
    __shared__ __align__(16) float sFeat[2][SPB][4];
    __shared__ float sQd[2][SPB][2];
    __shared__ __align__(16) float sDV[4][SPB][4]; // partials per jt2

    bf16* const sH1 = sBuf;        // 16KB H1^T B-frags [(st*4+kt)*64+l]*8 (G1^T in-place later)
    bf16* const sG2 = sBuf + 8192; // 16KB G2^T B-frags [(st*4+jt2)*64+l]*8

    const int tid  = threadIdx.x;
    const int w    = tid >> 6;
    const int lane = tid & 63;
    const int lrow = lane & 15;
    const int lq   = lane >> 4;
    const int wlo  = w & 3;
    const int whi  = w >> 2;

    // ---------------- one-time staging ----------------
    { // W1 rows (coalesced, 1 elem/thread) + biases/W3
        int r = tid >> 7, j = tid & (HID - 1);
        sW1r[r][j] = W1[r * HID + j];
    }
    if (tid < HID) sB1[tid] = b1[tid];
    else if (tid < 2 * HID) sB2[tid - HID] = b2[tid - HID];
    else if (tid < 3 * HID) sW3[tid - 2 * HID] = W3[tid - 2 * HID];

    // W2^T A-frags (column-segment gather) into sBuf, 4 frag lines/thread
    #pragma unroll
    for (int tt = 0; tt < 4; ++tt) {
        int e = tid + tt * TPB;       // 0..2047
        int t = e >> 6, l = e & 63;
        int jt = t >> 2, kt = t & 3;
        int lr = l & 15, q = l >> 4;
        bf16x8 f;
        #pragma unroll
        for (int idx = 0; idx < 8; ++idx)
            f[idx] = (bf16)W2[(32*kt + 8*q + idx) * HID + 16*jt + lr];
        *reinterpret_cast<bf16x8*>(&sBuf[e * 8]) = f;
    }
    // W1 A-frag for GEMM3t, K-range jt2=wlo (rows>=4 zero)
    bf16x8 bW1 = {};
    if (lrow < 4) {
        const float4* wp = reinterpret_cast<const float4*>(&W1[lrow*HID + 32*wlo + 8*lq]);
        float4 a = wp[0], b = wp[1];
        bW1[0]=(bf16)a.x; bW1[1]=(bf16)a.y; bW1[2]=(bf16)a.z; bW1[3]=(bf16)a.w;
        bW1[4]=(bf16)b.x; bW1[5]=(bf16)b.y; bW1[6]=(bf16)b.z; bW1[7]=(bf16)b.w;
    }
    // GEMM2t A-frags: W2 rows from global -> regs, once
    bf16x8 aW2[2][4];
    #pragma unroll
    for (int u = 0; u < 2; ++u) {
        const float* rbase = &W2[(16*(2*wlo + u) + lrow) * HID + 8*lq];
        #pragma unroll
        for (int jt2 = 0; jt2 < 4; ++jt2) {
            const float4* rp = reinterpret_cast<const float4*>(rbase + 32*jt2);
            float4 r0 = rp[0], r1 = rp[1];
            bf16x8 g;
            g[0]=(bf16)r0.x; g[1]=(bf16)r0.y; g[2]=(bf16)r0.z; g[3]=(bf16)r0.w;
            g[4]=(bf16)r1.x; g[5]=(bf16)r1.y; g[6]=(bf16)r1.z; g[7]=(bf16)r1.w;
            aW2[u][jt2] = g;
        }
    }
    // chunk-0 state prefetch (wave 7)
    if (tid >= TPB - SPB) {
        int s  = tid - (TPB - SPB);
        int g  = (int)blockIdx.x * SPB + s;
        int gc = g < B ? g : (B - 1);
        float4 x = reinterpret_cast<const float4*>(X)[gc];
        float s1, c1, s2, c2;
        __sincosf(x.x, &s1, &c1);
        __sincosf(x.y, &s2, &c2);
        sFeat[0][s][0]=s1; sFeat[0][s][1]=c1; sFeat[0][s][2]=s2; sFeat[0][s][3]=c2;
        sQd[0][s][0]=x.z;  sQd[0][s][1]=x.w;
    }
    __syncthreads(); // staging image of W2^T frags complete

    // GEMM1t A-frags: own (jt,kt) fragments LDS -> regs, then sBuf is reusable
    bf16x8 aW2T[2][4];
    #pragma unroll
    for (int u = 0; u < 2; ++u)
        #pragma unroll
        for (int kt = 0; kt < 4; ++kt)
            aW2T[u][kt] = *reinterpret_cast<const bf16x8*>(&sBuf[(((2*wlo+u)*4 + kt)*64 + lane)*8]);
    __syncthreads(); // all frag copies done; sBuf now free for sH1/sG2

    #pragma unroll 1
    for (int c = 0; c < nchunk; ++c) {
        const int par = c & 1;
        const int s0  = (c * GRIDB + (int)blockIdx.x) * SPB;

        // ---- Phase 1: H1^T B-frags; tile (st=wlo, kt=2whi+h); lane: s=16wlo+lrow ----
        {
            int s = 16 * wlo + lrow;
            float f0 = sFeat[par][s][0], f1 = sFeat[par][s][1];
            float f2 = sFeat[par][s][2], f3 = sFeat[par][s][3];
            #pragma unroll
            for (int h = 0; h < 2; ++h) {
                int kt = 2 * whi + h;
                int jb = 32 * kt + 8 * lq;
                floatx4 w0a = *reinterpret_cast<const floatx4*>(&sW1r[0][jb]);
                floatx4 w0b = *reinterpret_cast<const floatx4*>(&sW1r[0][jb+4]);
                floatx4 w1a = *reinterpret_cast<const floatx4*>(&sW1r[1][jb]);
                floatx4 w1b = *reinterpret_cast<const floatx4*>(&sW1r[1][jb+4]);
                floatx4 w2a = *reinterpret_cast<const floatx4*>(&sW1r[2][jb]);
                floatx4 w2b = *reinterpret_cast<const floatx4*>(&sW1r[2][jb+4]);
                floatx4 w3a = *reinterpret_cast<const floatx4*>(&sW1r[3][jb]);
                floatx4 w3b = *reinterpret_cast<const floatx4*>(&sW1r[3][jb+4]);
                floatx4 bba = *reinterpret_cast<const floatx4*>(&sB1[jb]);
                floatx4 bbb = *reinterpret_cast<const floatx4*>(&sB1[jb+4]);
                floatx4 za = bba + f0*w0a + f1*w1a + f2*w2a + f3*w3a; // 8 v_pk_fma
                floatx4 zb = bbb + f0*w0b + f1*w1b + f2*w2b + f3*w3b;
                floatx4 ha = tanh4(za);
                floatx4 hb = tanh4(zb);
                bf16x8 hf;
                hf[0]=(bf16)ha[0]; hf[1]=(bf16)ha[1]; hf[2]=(bf16)ha[2]; hf[3]=(bf16)ha[3];
                hf[4]=(bf16)hb[0]; hf[5]=(bf16)hb[1]; hf[6]=(bf16)hb[2]; hf[7]=(bf16)hb[3];
                *reinterpret_cast<bf16x8*>(&sH1[((wlo*4 + kt)*64 + lane)*8]) = hf;
            }
        }
        __syncthreads(); // B: sH1 ready

        // ---- GEMM1t: Z2^T = W2^T @ H1^T ; A from regs; out tiles (jt=2wlo+t, st=2whi+s) ----
        floatx4 acc[2][2];
        #pragma unroll
        for (int t = 0; t < 2; ++t)
            #pragma unroll
            for (int s = 0; s < 2; ++s) acc[t][s] = floatx4{0.f,0.f,0.f,0.f};
        #pragma unroll
        for (int kt = 0; kt < 4; ++kt) {
            bf16x8 b0 = *reinterpret_cast<const bf16x8*>(&sH1[(((2*whi  )*4 + kt)*64 + lane)*8]);
            bf16x8 b1v = *reinterpret_cast<const bf16x8*>(&sH1[(((2*whi+1)*4 + kt)*64 + lane)*8]);
            acc[0][0] = __builtin_amdgcn_mfma_f32_16x16x32_bf16(aW2T[0][kt], b0,  acc[0][0], 0,0,0);
            acc[0][1] = __builtin_amdgcn_mfma_f32_16x16x32_bf16(aW2T[0][kt], b1v, acc[0][1], 0,0,0);
            acc[1][0] = __builtin_amdgcn_mfma_f32_16x16x32_bf16(aW2T[1][kt], b0,  acc[1][0], 0,0,0);
            acc[1][1] = __builtin_amdgcn_mfma_f32_16x16x32_bf16(aW2T[1][kt], b1v, acc[1][1], 0,0,0);
        }

        // ---- Phase 3: G2^T = (1-tanh^2(Z2+b2))*W3 -> B-frags via ds_write_b64 ----
        #pragma unroll
        for (int t = 0; t < 2; ++t) {
            int jb = 16*(2*wlo + t) + 4*lq;   // j for r=0
            floatx4 b2v = *reinterpret_cast<const floatx4*>(&sB2[jb]);
            floatx4 w3v = *reinterpret_cast<const floatx4*>(&sW3[jb]);
            int q2  = 2*t + (lq >> 1);
            int sub = 4 * (lq & 1);
            #pragma unroll
            for (int s = 0; s < 2; ++s) {
                int st = 2*whi + s;
                floatx4 h = tanh4(acc[t][s] + b2v);
                floatx4 gv = (1.0f - h*h) * w3v;           // packed
                bf16x4 g;
                g[0]=(bf16)gv[0]; g[1]=(bf16)gv[1]; g[2]=(bf16)gv[2]; g[3]=(bf16)gv[3];
                *reinterpret_cast<bf16x4*>(&sG2[((st*4 + wlo)*64 + (q2*16 + lrow))*8 + sub]) = g;
            }
        }
        __syncthreads(); // C: sG2 (G2^T) ready

        // ---- GEMM2t: S^T = W2 @ G2^T ; out tiles (it=2wlo+u, st=2whi+s) ----
        #pragma unroll
        for (int t = 0; t < 2; ++t)
            #pragma unroll
            for (int s = 0; s < 2; ++s) acc[t][s] = floatx4{0.f,0.f,0.f,0.f};
        #pragma unroll
        for (int jt2 = 0; jt2 < 4; ++jt2) {
            bf16x8 g0 = *reinterpret_cast<const bf16x8*>(&sG2[(((2*whi  )*4 + jt2)*64 + lane)*8]);
            bf16x8 g1 = *reinterpret_cast<const bf16x8*>(&sG2[(((2*whi+1)*4 + jt2)*64 + lane)*8]);
            acc[0][0] = __builtin_amdgcn_mfma_f32_16x16x32_bf16(aW2[0][jt2], g0, acc[0][0], 0,0,0);
            acc[0][1] = __builtin_amdgcn_mfma_f32_16x16x32_bf16(aW2[0][jt2], g1, acc[0][1], 0,0,0);
            acc[1][0] = __builtin_amdgcn_mfma_f32_16x16x32_bf16(aW2[1][jt2], g0, acc[1][0], 0,0,0);
            acc[1][1] = __builtin_amdgcn_mfma_f32_16x16x32_bf16(aW2[1][jt2], g1, acc[1][1], 0,0,0);
        }
        // (no barrier: phase5 below touches only wave-private sH1 slots)

        // ---- Phase 5: G1^T = (1-h1^2)*S^T, IN-PLACE in sH1 (own slots, b64 RMW) ----
        #pragma unroll
        for (int u = 0; u < 2; ++u) {
            int q2  = 2*u + (lq >> 1);
            int sub = 4 * (lq & 1);
            #pragma unroll
            for (int s = 0; s < 2; ++s) {
                int st  = 2*whi + s;
                int off = ((st*4 + wlo)*64 + (q2*16 + lrow))*8 + sub;
                bf16x4 h4 = *reinterpret_cast<const bf16x4*>(&sH1[off]);
                floatx4 hf = { (float)h4[0], (float)h4[1], (float)h4[2], (float)h4[3] };
                floatx4 gv = (1.0f - hf*hf) * acc[u][s];   // packed
                bf16x4 g;
                g[0]=(bf16)gv[0]; g[1]=(bf16)gv[1]; g[2]=(bf16)gv[2]; g[3]=(bf16)gv[3];
                *reinterpret_cast<bf16x4*>(&sH1[off]) = g;
            }
        }

        // prefetch next chunk's state (wave 7), overlapped with GEMM3t
        if (tid >= TPB - SPB && c + 1 < nchunk) {
            int s  = tid - (TPB - SPB);
            int g  = ((c + 1) * GRIDB + (int)blockIdx.x) * SPB + s;
            int gc = g < B ? g : (B - 1);
            float4 x = reinterpret_cast<const float4*>(X)[gc];
            float s1, c1, s2, c2;
            __sincosf(x.x, &s1, &c1);
            __sincosf(x.y, &s2, &c2);
            int np = par ^ 1;
            sFeat[np][s][0]=s1; sFeat[np][s][1]=c1; sFeat[np][s][2]=s2; sFeat[np][s][3]=c2;
            sQd[np][s][0]=x.z;  sQd[np][s][1]=x.w;
        }

        // ---- GEMM3t: dV^T partial (jt2=wlo) = W1 @ G1^T (same-wave tiles, from sH1) ----
        {
            bf16x8 g0 = *reinterpret_cast<const bf16x8*>(&sH1[(((2*whi  )*4 + wlo)*64 + lane)*8]);
            bf16x8 g1 = *reinterpret_cast<const bf16x8*>(&sH1[(((2*whi+1)*4 + wlo)*64 + lane)*8]);
            floatx4 d0 = __builtin_amdgcn_mfma_f32_16x16x32_bf16(bW1, g0, floatx4{0.f,0.f,0.f,0.f}, 0,0,0);
            floatx4 d1 = __builtin_amdgcn_mfma_f32_16x16x32_bf16(bW1, g1, floatx4{0.f,0.f,0.f,0.f}, 0,0,0);
            if (lane < 16) { // quad 0: regs r = dV[k=r] for sample s=16st+lane
                *reinterpret_cast<float4*>(&sDV[wlo][16*(2*whi  ) + lane][0]) =
                    make_float4(d0[0], d0[1], d0[2], d0[3]);
                *reinterpret_cast<float4*>(&sDV[wlo][16*(2*whi+1) + lane][0]) =
                    make_float4(d1[0], d1[1], d1[2], d1[3]);
            }
        }
        __syncthreads(); // F: sDV + next-chunk state visible

        // ---- Epilogue: analytic dynamics + 2x2 solve (wave 0, tid<64) ----
        if (tid < SPB) {
            int g = s0 + tid;
            if (g < B) {
                floatx4 d0 = *reinterpret_cast<const floatx4*>(&sDV[0][tid][0]);
                floatx4 d1 = *reinterpret_cast<const floatx4*>(&sDV[1][tid][0]);
                floatx4 d2 = *reinterpret_cast<const floatx4*>(&sDV[2][tid][0]);
                floatx4 d3 = *reinterpret_cast<const floatx4*>(&sDV[3][tid][0]);
                floatx4 dV = (d0 + d1) + (d2 + d3);        // packed
                float s1 = sFeat[par][tid][0], c1 = sFeat[par][tid][1];
                float s2 = sFeat[par][tid][2], c2 = sFeat[par][tid][3];
                float w1 = sQd[par][tid][0],  w2 = sQd[par][tid][1];
                float cosD = c1 * c2 + s1 * s2;
                float sinD = s1 * c2 - c1 * s2;
                float dVt1 = dV[0] * c1 - dV[1] * s1;   // dV/dt1
                float dVt2 = dV[2] * c2 - dV[3] * s2;   // dV/dt2
                float sT = w1 * w2 * sinD;              // dT/dt1 = -sT, dT/dt2 = +sT
                float cw = sinD * (w2 - w1);
                float rhs1 = (-sT - dVt1) - w2 * cw;
                float rhs2 = ( sT - dVt2) - w1 * cw;
                float det = 2.0f - cosD * cosD;         // det(M) in [1,2]
                float inv = __builtin_amdgcn_rcpf(det);
                float qdd1 = (rhs1 - cosD * rhs2) * inv;
                float qdd2 = (2.0f * rhs2 - cosD * rhs1) * inv;
                *reinterpret_cast<float4*>(&out[4 * g]) = make_float4(w1, w2, qdd1, qdd2);
            }
        }
    }
}

extern "C" void kernel_launch(void* const* d_in, const int* in_sizes, int n_in,
                              void* d_out, int out_size, void* d_ws, size_t ws_size,
                              hipStream_t stream) {
    const float* X  = (const float*)d_in[0];
    const float* W1 = (const float*)d_in[1];
    const float* b1 = (const float*)d_in[2];
    const float* W2 = (const float*)d_in[3];
    const float* b2 = (const float*)d_in[4];
    const float* W3 = (const float*)d_in[5];
    // d_in[6] = b3: constant offset on V, vanishes in all gradients
    float* out = (float*)d_out;
    int B = in_sizes[0] / 4;
    int nchunk = (B + GRIDB * SPB - 1) / (GRIDB * SPB);
    lnn_kernel<<<GRIDB, TPB, 0, stream>>>(X, W1, b1, b2, W3, W2, out, B, nchunk);
}

// Round 6
// 88.609 us; speedup vs baseline: 1.5134x; 1.0274x over previous
//
#include <hip/hip_runtime.h>
#include <math.h>

#define HID 128
#define TPB 1024  // 16 waves; 1 block/CU (147.5KB LDS) -> 4 waves/SIMD
#define NW  16    // waves per block
#define GRIDB 256 // 1 block per CU

typedef __bf16 bf16;
typedef bf16 bf16x8 __attribute__((ext_vector_type(8)));
typedef bf16 bf16x4 __attribute__((ext_vector_type(4)));
typedef float floatx4 __attribute__((ext_vector_type(4)));

// rcp-based tanh; packed f32 (v_pk_*) for everything but the trans ops.
__device__ __forceinline__ floatx4 tanh4(floatx4 z) {
    floatx4 t = z * 2.885390081777927f;                  // exp(2x) via exp2
    floatx4 e = { __builtin_amdgcn_exp2f(t[0]), __builtin_amdgcn_exp2f(t[1]),
                  __builtin_amdgcn_exp2f(t[2]), __builtin_amdgcn_exp2f(t[3]) };
    e = e + 1.0f;
    floatx4 r = { __builtin_amdgcn_rcpf(e[0]), __builtin_amdgcn_rcpf(e[1]),
                  __builtin_amdgcn_rcpf(e[2]), __builtin_amdgcn_rcpf(e[3]) };
    return 1.0f - 2.0f * r;
}

// WAVE-AUTONOMOUS all-transposed formulation. Each wave owns ONE 16-sample
// MFMA tile end-to-end; ZERO barriers in the main loop (r3 post-mortem:
// lockstep barriers + exposed latency were ~8x over the pipe floor).
// MFMA 16x16x32 layouts:
//   A-frag: lane holds A[m=lane&15][k=(lane>>4)*8+idx]
//   B-frag: lane holds B[k=(lane>>4)*8+idx][n=lane&15]
//   C/D:    lane/reg holds D[row=(lane>>4)*4+reg][col=lane&15]
// Sample ALWAYS = lane&15 (column) => phase1 output IS the GEMM1 B-frag in
// registers (no LDS, no cross-wave). Cross-lane C->B-frag transforms happen
// in per-wave LDS scratch with lgkmcnt only (same proven index formulas as
// the old 8-wave kernel).
// GEMM1t: Z2^T = W2^T @ H1^T   (A-lines from shared sW2A, B=breg)
// GEMM2t: S^T  = W2 @ G2^T     (A-lines from shared sW2R, B via 1KB scratch)
// GEMM3t: dV^T = W1 @ G1^T     (A=bW1 regs, B=G1 in-place over sH1w)
// LDS-BW roofline of this design: 64 shared-A-line ds_read_b128 per tile
// (~12cyc each) vs 68 MFMA (~4.85cyc) -> LDS-pipe-bound, ~10-12us kernel.

__global__ __launch_bounds__(TPB, 4)
void lnn_kernel(const float* __restrict__ X,
                const float* __restrict__ W1,
                const float* __restrict__ b1,
                const float* __restrict__ b2,
                const float* __restrict__ W3,
                const float* __restrict__ W2,
                float* __restrict__ out,
                int B, int nchunk)
{
    // 32KB: W2^T A-frags [(jt*4+kt)*64+lane]*8 : lane(q,lr) = W2[32kt+8q+idx][16jt+lr]
    __shared__ __align__(16) bf16 sW2A[16384];
    // 32KB: W2 row A-frags [(it*4+jt2)*64+lane]*8 : lane(q,lr) = W2[16it+lr][32jt2+8q+idx]
    __shared__ __align__(16) bf16 sW2R[16384];
    // 64KB: per-wave 4 B-frag lines (H1^T, then G1^T in-place)
    __shared__ __align__(16) bf16 sH1w[NW][2048];
    // 16KB: per-wave 1-line G2^T transform buffer (reused per jt2)
    __shared__ __align__(16) bf16 sGl[NW][512];
    __shared__ __align__(16) float sW1r[4][HID]; // W1 row-major
    __shared__ __align__(16) float sB1[HID], sB2[HID], sW3[HID];

    const int tid  = threadIdx.x;
    const int w    = tid >> 6;
    const int lane = tid & 63;
    const int lrow = lane & 15;
    const int lq   = lane >> 4;

    // ---------------- one-time staging ----------------
    if (tid < 512) { int r = tid >> 7, j = tid & (HID - 1); sW1r[r][j] = W1[r * HID + j]; }
    if (tid < HID) sB1[tid] = b1[tid];
    else if (tid < 2 * HID) sB2[tid - HID] = b2[tid - HID];
    else if (tid < 3 * HID) sW3[tid - 2 * HID] = W3[tid - 2 * HID];

    #pragma unroll
    for (int tt = 0; tt < 2; ++tt) {
        int e = tid + tt * TPB;       // 0..2047 frag-line slots
        int t = e >> 6, l = e & 63;
        int a = t >> 2, bidx = t & 3; // (jt,kt) for sW2A ; (it,jt2) for sW2R
        int lr = l & 15, q = l >> 4;
        bf16x8 f;
        #pragma unroll
        for (int idx = 0; idx < 8; ++idx)
            f[idx] = (bf16)W2[(32*bidx + 8*q + idx) * HID + 16*a + lr];
        *reinterpret_cast<bf16x8*>(&sW2A[e * 8]) = f;
        const float4* rp = reinterpret_cast<const float4*>(&W2[(16*a + lr) * HID + 32*bidx + 8*q]);
        float4 r0 = rp[0], r1 = rp[1];
        bf16x8 g;
        g[0]=(bf16)r0.x; g[1]=(bf16)r0.y; g[2]=(bf16)r0.z; g[3]=(bf16)r0.w;
        g[4]=(bf16)r1.x; g[5]=(bf16)r1.y; g[6]=(bf16)r1.z; g[7]=(bf16)r1.w;
        *reinterpret_cast<bf16x8*>(&sW2R[e * 8]) = g;
    }
    // W1 A-frags for GEMM3 (4 kt lines), rows>=4 zero
    bf16x8 bW1[4];
    #pragma unroll
    for (int m = 0; m < 4; ++m) { bf16x8 z = {}; bW1[m] = z; }
    if (lrow < 4) {
        #pragma unroll
        for (int m = 0; m < 4; ++m) {
            const float4* wp = reinterpret_cast<const float4*>(&W1[lrow*HID + 32*m + 8*lq]);
            float4 a = wp[0], b = wp[1];
            bW1[m][0]=(bf16)a.x; bW1[m][1]=(bf16)a.y; bW1[m][2]=(bf16)a.z; bW1[m][3]=(bf16)a.w;
            bW1[m][4]=(bf16)b.x; bW1[m][5]=(bf16)b.y; bW1[m][6]=(bf16)b.z; bW1[m][7]=(bf16)b.w;
        }
    }
    __syncthreads(); // ONLY barrier in the kernel

    bf16* const myH = &sH1w[w][0];
    bf16* const myG = &sGl[w][0];

    const int tileStride = GRIDB * NW;          // tiles per chunk-round
    const int t0 = (int)blockIdx.x * NW + w;    // this wave's first tile
    // all 64 lanes hold sample lrow's state (4-way redundant, same cacheline)
    int gc0 = t0 * 16 + lrow; gc0 = gc0 < B ? gc0 : (B - 1);
    float4 xc = reinterpret_cast<const float4*>(X)[gc0];

    #pragma unroll 1
    for (int c = 0; c < nchunk; ++c) {
        const int tile = t0 + c * tileStride;
        if (tile * 16 >= B) break;              // per-wave divergence OK: no barriers
        const int S0 = tile * 16;

        float s1, c1, s2, c2;
        __sincosf(xc.x, &s1, &c1);
        __sincosf(xc.y, &s2, &c2);
        const float qd1 = xc.z, qd2 = xc.w;

        // prefetch next tile's state (latency hidden under whole tile body)
        float4 xn = xc;
        {
            int tn = tile + tileStride;
            if (tn * 16 < B) {
                int gc = tn * 16 + lrow; gc = gc < B ? gc : (B - 1);
                xn = reinterpret_cast<const float4*>(X)[gc];
            }
        }

        // ---- Phase 1: H1^T B-frags DIRECT in regs (+copy to myH for phase5) ----
        bf16x8 breg[4];
        #pragma unroll
        for (int kt = 0; kt < 4; ++kt) {
            int jb = 32 * kt + 8 * lq;
            floatx4 w0a = *reinterpret_cast<const floatx4*>(&sW1r[0][jb]);
            floatx4 w0b = *reinterpret_cast<const floatx4*>(&sW1r[0][jb+4]);
            floatx4 w1a = *reinterpret_cast<const floatx4*>(&sW1r[1][jb]);
            floatx4 w1b = *reinterpret_cast<const floatx4*>(&sW1r[1][jb+4]);
            floatx4 w2a = *reinterpret_cast<const floatx4*>(&sW1r[2][jb]);
            floatx4 w2b = *reinterpret_cast<const floatx4*>(&sW1r[2][jb+4]);
            floatx4 w3a = *reinterpret_cast<const floatx4*>(&sW1r[3][jb]);
            floatx4 w3b = *reinterpret_cast<const floatx4*>(&sW1r[3][jb+4]);
            floatx4 bba = *reinterpret_cast<const floatx4*>(&sB1[jb]);
            floatx4 bbb = *reinterpret_cast<const floatx4*>(&sB1[jb+4]);
            floatx4 za = bba + s1*w0a + c1*w1a + s2*w2a + c2*w3a;
            floatx4 zb = bbb + s1*w0b + c1*w1b + s2*w2b + c2*w3b;
            floatx4 ha = tanh4(za);
            floatx4 hb = tanh4(zb);
            bf16x8 hf;
            hf[0]=(bf16)ha[0]; hf[1]=(bf16)ha[1]; hf[2]=(bf16)ha[2]; hf[3]=(bf16)ha[3];
            hf[4]=(bf16)hb[0]; hf[5]=(bf16)hb[1]; hf[6]=(bf16)hb[2]; hf[7]=(bf16)hb[3];
            breg[kt] = hf;
            *reinterpret_cast<bf16x8*>(&myH[(kt*64 + lane)*8]) = hf; // for phase5 reads
        }

        // ---- GEMM1t: Z2^T = W2^T @ H1^T ; acc[jt], jt=0..7 ----
        floatx4 acc[8];
        #pragma unroll
        for (int jt = 0; jt < 8; ++jt) acc[jt] = floatx4{0.f,0.f,0.f,0.f};
        #pragma unroll
        for (int jt = 0; jt < 8; ++jt)
            #pragma unroll
            for (int kt = 0; kt < 4; ++kt)
                acc[jt] = __builtin_amdgcn_mfma_f32_16x16x32_bf16(
                    *reinterpret_cast<const bf16x8*>(&sW2A[((jt*4 + kt)*64 + lane)*8]),
                    breg[kt], acc[jt], 0,0,0);

        // ---- Phase 3 + GEMM2t fused per jt2 (1KB wave-private line buffer) ----
        floatx4 acc2[8];
        #pragma unroll
        for (int it = 0; it < 8; ++it) acc2[it] = floatx4{0.f,0.f,0.f,0.f};
        #pragma unroll
        for (int jt2 = 0; jt2 < 4; ++jt2) {
            #pragma unroll
            for (int b = 0; b < 2; ++b) {
                int jt = 2*jt2 + b;
                int jb = 16*jt + 4*lq;
                floatx4 b2v = *reinterpret_cast<const floatx4*>(&sB2[jb]);
                floatx4 w3v = *reinterpret_cast<const floatx4*>(&sW3[jb]);
                floatx4 h = tanh4(acc[jt] + b2v);
                floatx4 gv = (1.0f - h*h) * w3v;
                bf16x4 g;
                g[0]=(bf16)gv[0]; g[1]=(bf16)gv[1]; g[2]=(bf16)gv[2]; g[3]=(bf16)gv[3];
                *reinterpret_cast<bf16x4*>(&myG[((2*b + (lq>>1))*16 + lrow)*8 + 4*(lq&1)]) = g;
            }
            // same-wave RAW on myG: DS ops execute in wave order; compiler emits lgkmcnt
            bf16x8 gB = *reinterpret_cast<const bf16x8*>(&myG[lane*8]);
            #pragma unroll
            for (int it = 0; it < 8; ++it)
                acc2[it] = __builtin_amdgcn_mfma_f32_16x16x32_bf16(
                    *reinterpret_cast<const bf16x8*>(&sW2R[((it*4 + jt2)*64 + lane)*8]),
                    gB, acc2[it], 0,0,0);
        }

        // ---- Phase 5: G1^T = (1-h1^2)*S^T, in-place b64 RMW over myH ----
        #pragma unroll
        for (int it = 0; it < 8; ++it) {
            int off = ((it>>1)*64 + ((2*(it&1) + (lq>>1))*16 + lrow))*8 + 4*(lq&1);
            bf16x4 h4 = *reinterpret_cast<const bf16x4*>(&myH[off]);
            floatx4 hf = { (float)h4[0], (float)h4[1], (float)h4[2], (float)h4[3] };
            floatx4 gv = (1.0f - hf*hf) * acc2[it];
            bf16x4 g;
            g[0]=(bf16)gv[0]; g[1]=(bf16)gv[1]; g[2]=(bf16)gv[2]; g[3]=(bf16)gv[3];
            *reinterpret_cast<bf16x4*>(&myH[off]) = g;
        }

        // ---- GEMM3t: dV^T = W1 @ G1^T, full K in-wave ----
        floatx4 dv = floatx4{0.f,0.f,0.f,0.f};
        #pragma unroll
        for (int m = 0; m < 4; ++m)
            dv = __builtin_amdgcn_mfma_f32_16x16x32_bf16(
                bW1[m],
                *reinterpret_cast<const bf16x8*>(&myH[(m*64 + lane)*8]),
                dv, 0,0,0);

        // ---- Epilogue: lanes 0..15 hold dv rows 0..3 for sample lrow ----
        if (lane < 16 && S0 + lane < B) {
            float dV0 = dv[0], dV1 = dv[1], dV2 = dv[2], dV3 = dv[3];
            float cosD = c1 * c2 + s1 * s2;
            float sinD = s1 * c2 - c1 * s2;
            float dVt1 = dV0 * c1 - dV1 * s1;   // dV/dt1
            float dVt2 = dV2 * c2 - dV3 * s2;   // dV/dt2
            float sT = qd1 * qd2 * sinD;        // dT/dt1 = -sT, dT/dt2 = +sT
            float cw = sinD * (qd2 - qd1);
            float rhs1 = (-sT - dVt1) - qd2 * cw;
            float rhs2 = ( sT - dVt2) - qd1 * cw;
            float det = 2.0f - cosD * cosD;     // det(M) in [1,2]
            float inv = __builtin_amdgcn_rcpf(det);
            float qdd1 = (rhs1 - cosD * rhs2) * inv;
            float qdd2 = (2.0f * rhs2 - cosD * rhs1) * inv;
            *reinterpret_cast<float4*>(&out[4 * (S0 + lane)]) = make_float4(qd1, qd2, qdd1, qdd2);
        }
        xc = xn;
    }
}

extern "C" void kernel_launch(void* const* d_in, const int* in_sizes, int n_in,
                              void* d_out, int out_size, void* d_ws, size_t ws_size,
                              hipStream_t stream) {
    const float* X  = (const float*)d_in[0];
    const float* W1 = (const float*)d_in[1];
    const float* b1 = (const float*)d_in[2];
    const float* W2 = (const float*)d_in[3];
    const float* b2 = (const float*)d_in[4];
    const float* W3 = (const float*)d_in[5];
    // d_in[6] = b3: constant offset on V, vanishes in all gradients
    float* out = (float*)d_out;
    int B = in_sizes[0] / 4;
    int tiles = (B + 15) >> 4;
    int nchunk = (tiles + GRIDB * NW - 1) / (GRIDB * NW);
    lnn_kernel<<<GRIDB, TPB, 0, stream>>>(X, W1, b1, b2, W3, W2, out, B, nchunk);
}